// Round 15
// baseline (327.427 us; speedup 1.0000x reference)
//
#include <hip/hip_runtime.h>

typedef _Float16 half8 __attribute__((ext_vector_type(8)));
typedef _Float16 half4 __attribute__((ext_vector_type(4)));
typedef float f32x4 __attribute__((ext_vector_type(4)));

__device__ __forceinline__ void lds_load16(const void* g, void* l) {
  __builtin_amdgcn_global_load_lds((const __attribute__((address_space(1))) void*)g,
                                   (__attribute__((address_space(3))) void*)l, 16, 0, 0);
}

__device__ __forceinline__ void lds_barrier() {
  asm volatile("s_waitcnt lgkmcnt(0)" ::: "memory");
  asm volatile("s_barrier" ::: "memory");
}

// ---------------- convert X f32 -> fp16 ----------------
__global__ __launch_bounds__(256) void cvt_x(const float* __restrict__ in,
                                             _Float16* __restrict__ out) {
  int i = blockIdx.x * 256 + threadIdx.x;
  const float4* p = (const float4*)(in + (size_t)i * 8);
  float4 a = p[0], b = p[1];
  half8 v;
  v[0] = (_Float16)a.x; v[1] = (_Float16)a.y; v[2] = (_Float16)a.z; v[3] = (_Float16)a.w;
  v[4] = (_Float16)b.x; v[5] = (_Float16)b.y; v[6] = (_Float16)b.z; v[7] = (_Float16)b.w;
  *(half8*)(out + (size_t)i * 8) = v;
}

// ------- convert + transpose weights: Wt[n][k] = W[k][n], fp16 -------
__global__ __launch_bounds__(256) void cvt_w(const float* __restrict__ Wq, const float* __restrict__ Wk,
                                             const float* __restrict__ Wv, const float* __restrict__ Wo,
                                             _Float16* __restrict__ Wqkvt, _Float16* __restrict__ Wot) {
  int id = blockIdx.x * 256 + threadIdx.x;
  int part = id / 589824;
  int r = id - part * 589824;
  int k = r / 768;
  int n = r - k * 768;
  const float* W = part == 0 ? Wq : part == 1 ? Wk : part == 2 ? Wv : Wo;
  _Float16 v = (_Float16)W[(size_t)k * 768 + n];
  if (part < 3) Wqkvt[((size_t)(part * 768 + n)) * 768 + k] = v;
  else          Wot[(size_t)n * 768 + k] = v;
}

// ---------------- fp16 MFMA GEMM: 128x128, BK=32, 4 waves, 4 blocks/CU (R11) ----------------
template <int EPI, int NB>
__global__ __launch_bounds__(256, 4) void gemm128(
    const _Float16* __restrict__ A, const _Float16* __restrict__ Bt,
    const float* __restrict__ b0, const float* __restrict__ b1, const float* __restrict__ b2,
    _Float16* __restrict__ Qo, _Float16* __restrict__ Ko, _Float16* __restrict__ Vto,
    float* __restrict__ Co) {
  __shared__ _Float16 Ab[2][128 * 32];
  __shared__ _Float16 Bb[2][128 * 32];
  const int tid = threadIdx.x, w = tid >> 6, l = tid & 63;
  const int lr = l & 15, lk = l >> 4;
  const int wm = w >> 1, wn = w & 1;
  const int q8 = (int)gridDim.x >> 3;
  const int wg = ((int)blockIdx.x & 7) * q8 + ((int)blockIdx.x >> 3);
  const int m0 = (wg / NB) * 128, n0 = (wg % NB) * 128;

  auto STAGE = [&](int kt, int dstb) {
#pragma unroll
    for (int i = 0; i < 2; ++i) {
      const int g = i * 256 + tid;
      const int row = g >> 2;
      const int gr = (g & 3) ^ (row & 3);
      lds_load16(A + (size_t)(m0 + row) * 768 + kt * 32 + gr * 8,
                 (char*)&Ab[dstb][0] + g * 16);
      lds_load16(Bt + (size_t)(n0 + row) * 768 + kt * 32 + gr * 8,
                 (char*)&Bb[dstb][0] + g * 16);
    }
  };

  f32x4 acc[4][4] = {};
  STAGE(0, 0);
  const int swzg = ((lk ^ (lr & 3)) * 8);

  for (int T = 0; T < 24; ++T) {
    const int b = T & 1;
    asm volatile("s_waitcnt vmcnt(0)" ::: "memory");
    asm volatile("s_barrier" ::: "memory");
    if (T < 23) STAGE(T + 1, b ^ 1);
    half8 af[4], bf[4];
#pragma unroll
    for (int mi = 0; mi < 4; ++mi)
      af[mi] = *(const half8*)&Ab[b][(wm * 64 + mi * 16 + lr) * 32 + swzg];
#pragma unroll
    for (int ni = 0; ni < 4; ++ni)
      bf[ni] = *(const half8*)&Bb[b][(wn * 64 + ni * 16 + lr) * 32 + swzg];
    __builtin_amdgcn_s_setprio(1);
#pragma unroll
    for (int mi = 0; mi < 4; ++mi)
#pragma unroll
      for (int ni = 0; ni < 4; ++ni)
        acc[mi][ni] = __builtin_amdgcn_mfma_f32_16x16x32_f16(af[mi], bf[ni], acc[mi][ni], 0, 0, 0);
    __builtin_amdgcn_s_setprio(0);
  }

#pragma unroll
  for (int mi = 0; mi < 4; ++mi) {
    const int rbase = m0 + wm * 64 + mi * 16 + lk * 4;
#pragma unroll
    for (int ni = 0; ni < 4; ++ni) {
      const int col = n0 + wn * 64 + ni * 16 + lr;
      if (EPI == 0) {
        const int part = col / 768;
        const int e = col - part * 768;
        const int h = e / 96, d = e - (e / 96) * 96;
        const float* bb = part == 0 ? b0 : part == 1 ? b1 : b2;
        const float bv = bb[e];
#pragma unroll
        for (int j = 0; j < 4; ++j) {
          const int row = rbase + j;
          const int bI = row >> 10, s = row & 1023;
          const int bh = bI * 8 + h;
          const _Float16 v = (_Float16)(acc[mi][ni][j] + bv);
          if (part < 2) {
            const size_t idx = ((((size_t)(bh * 64 + (s >> 4)) * 3 + (d >> 5)) * 64
                                + ((d & 31) >> 3) * 16 + (s & 15)) << 3) + (d & 7);
            if (part == 0) Qo[idx] = v; else Ko[idx] = v;
          } else {
            const size_t idx = ((((size_t)(bh * 6 + (d >> 4)) * 32 + (s >> 5)) * 64
                                + ((s & 31) >> 3) * 16 + (d & 15)) << 3) + (s & 7);
            Vto[idx] = v;
          }
        }
      } else {
        const float bv = b0[col];
#pragma unroll
        for (int j = 0; j < 4; ++j) {
          const int row = rbase + j;
          __builtin_nontemporal_store(acc[mi][ni][j] + bv, Co + (size_t)row * 768 + col);
        }
      }
    }
  }
}

// ---------------- fused attention v12: 16 q-rows, batched loads, 2 blocks/CU ----------------
// VGPR <=128 by construction: K-frags in two 4-tile batches (48 regs), V after
// QK^T in two [6][2] batches (24 regs), kf/vf never co-live. Probs via the
// PROVEN v8 path: f32 P -> LDS -> 2x512B NT wave-stores. LDS 68KB, (512,4)
// -> 2 blocks/CU so one block's QK^T overlaps the other's store/PV.
__global__ __launch_bounds__(512, 4) void attn(const _Float16* __restrict__ swzQ,
                                               const _Float16* __restrict__ swzK,
                                               const _Float16* __restrict__ swzV,
                                               float* __restrict__ probs,
                                               _Float16* __restrict__ ctx) {
  __shared__ __align__(16) float Pf[8][16][132];
  __shared__ float lsb[8][16];
  const int tid = threadIdx.x, w = tid >> 6, l = tid & 63;
  const int lr = l & 15, lk = l >> 4;
  const int id = blockIdx.x;
  const int lid = (id & 7) * 1024 + (id >> 3);   // XCD-chunked (8192 blocks)
  const int bh = lid >> 6, qt = lid & 63;
  const int q0 = qt * 16;
  const float SC = 0.10206207261596577f * 1.4426950408889634f;  // (1/sqrt(96)) * log2(e)

  const half8* qb  = (const half8*)swzQ + (size_t)(bh * 64 + qt) * 192;
  const half8* kb  = (const half8*)swzK + (size_t)(bh * 64 + w * 8) * 192;
  const half8* vb0 = (const half8*)swzV + (size_t)bh * 12288;

  half8 bq[3];
#pragma unroll
  for (int kk = 0; kk < 3; ++kk) bq[kk] = qb[kk * 64 + l];

  // ---- QK^T: two 4-tile K batches (48 VGPR live), scores in 8 f32x4 ----
  f32x4 s[8];
#pragma unroll
  for (int cb = 0; cb < 2; ++cb) {
    half8 kf[4][3];
#pragma unroll
    for (int t = 0; t < 4; ++t)
#pragma unroll
      for (int kk = 0; kk < 3; ++kk)
        kf[t][kk] = kb[((cb * 4 + t) * 3 + kk) * 64 + l];
#pragma unroll
    for (int t = 0; t < 4; ++t) {
      f32x4 acc = {0.f, 0.f, 0.f, 0.f};
#pragma unroll
      for (int kk = 0; kk < 3; ++kk)
        acc = __builtin_amdgcn_mfma_f32_16x16x32_f16(kf[t][kk], bq[kk], acc, 0, 0, 0);
      s[cb * 4 + t] = acc;
    }
  }

  // ---- exp + per-lane partial sum; cross-wave reduce ----
  float psum = 0.f;
#pragma unroll
  for (int ct = 0; ct < 8; ++ct)
#pragma unroll
    for (int j = 0; j < 4; ++j) {
      const float e = __builtin_amdgcn_exp2f(s[ct][j] * SC);
      s[ct][j] = e;
      psum += e;
    }
  psum += __shfl_xor(psum, 16);
  psum += __shfl_xor(psum, 32);
  if (lk == 0) lsb[w][lr] = psum;
  lds_barrier();                                    // B1
  float lt = 0.f;
#pragma unroll
  for (int ww = 0; ww < 8; ++ww) lt += lsb[ww][lr];
  const float invl = 1.f / lt;

  // ---- normalized f32 P -> wave-local LDS tile ----
#pragma unroll
  for (int ct = 0; ct < 8; ++ct) {
    f32x4 p4;
#pragma unroll
    for (int j = 0; j < 4; ++j) p4[j] = s[ct][j] * invl;
    *(f32x4*)&Pf[w][lr][ct * 16 + lk * 4] = p4;
  }

  // ---- probs: repacked reads (2 rows x 512B) -> NT stores (proven v8 path) ----
  {
    float* pbase = probs + ((size_t)bh << 20) + (size_t)q0 * 1024 + w * 128;
    const int qh = l >> 5, c4 = (l & 31) * 4;
#pragma unroll
    for (int r2 = 0; r2 < 8; ++r2) {
      const int q = r2 * 2 + qh;
      f32x4 v = *(const f32x4*)&Pf[w][q][c4];
      __builtin_nontemporal_store(v, (f32x4*)(pbase + (size_t)q * 1024 + c4));
    }
  }

  // ---- PV: P from LDS, V in two [6][2] batches (24 regs; kf dead by now) ----
  f32x4 cacc[6] = {};
#pragma unroll
  for (int kb2 = 0; kb2 < 2; ++kb2) {
    half8 vf[6][2];
#pragma unroll
    for (int dt = 0; dt < 6; ++dt)
#pragma unroll
      for (int t = 0; t < 2; ++t)
        vf[dt][t] = vb0[(dt * 32 + w * 4 + kb2 * 2 + t) * 64 + l];
#pragma unroll
    for (int t = 0; t < 2; ++t) {
      const int kk = kb2 * 2 + t;
      f32x4 a0 = *(const f32x4*)&Pf[w][lr][kk * 32 + lk * 8];
      f32x4 a1 = *(const f32x4*)&Pf[w][lr][kk * 32 + lk * 8 + 4];
      half8 pa;
#pragma unroll
      for (int e = 0; e < 4; ++e) { pa[e] = (_Float16)a0[e]; pa[4 + e] = (_Float16)a1[e]; }
#pragma unroll
      for (int dt = 0; dt < 6; ++dt)
        cacc[dt] = __builtin_amdgcn_mfma_f32_16x16x32_f16(pa, vf[dt][t], cacc[dt], 0, 0, 0);
    }
  }

  // ---- wave-local partial -> own LDS region (per-wave DS ordering) ----
  float* cbw = (float*)&Pf[w][0][0];   // [16][100] reuse
#pragma unroll
  for (int dt = 0; dt < 6; ++dt)
#pragma unroll
    for (int j = 0; j < 4; ++j)
      cbw[(lk * 4 + j) * 100 + dt * 16 + lr] = cacc[dt][j];
  lds_barrier();                                    // B2

  // ---- cross-wave reduce (8 partials) + ctx store ----
  const int rq = tid >> 5;            // 0..15
  const int rd0 = (tid & 31) * 3;     // 0..93
  const int b = bh >> 3, h = bh & 7;
  _Float16* cg = ctx + ((size_t)(b * 1024 + q0 + rq)) * 768 + h * 96 + rd0;
#pragma unroll
  for (int e = 0; e < 3; ++e) {
    float v = 0.f;
#pragma unroll
    for (int ww = 0; ww < 8; ++ww) v += ((const float*)&Pf[ww][0][0])[rq * 100 + rd0 + e];
    cg[e] = (_Float16)v;
  }
}

extern "C" void kernel_launch(void* const* d_in, const int* in_sizes, int n_in,
                              void* d_out, int out_size, void* d_ws, size_t ws_size,
                              hipStream_t stream) {
  (void)in_sizes; (void)n_in; (void)out_size; (void)ws_size;
  const float* X  = (const float*)d_in[0];
  const float* Wq = (const float*)d_in[1];
  const float* bq = (const float*)d_in[2];
  const float* Wk = (const float*)d_in[3];
  const float* bk = (const float*)d_in[4];
  const float* Wv = (const float*)d_in[5];
  const float* bv = (const float*)d_in[6];
  const float* Wo = (const float*)d_in[7];
  const float* bo = (const float*)d_in[8];

  char* ws = (char*)d_ws;
  _Float16* Xh    = (_Float16*)(ws + 0);          // 16384x768 fp16      (25165824 B)
  _Float16* Wqkvt = (_Float16*)(ws + 25165824);   // 2304x768 fp16       ( 3538944 B)
  _Float16* Wot   = (_Float16*)(ws + 28704768);   // 768x768 fp16        ( 1179648 B)
  _Float16* Qh    = (_Float16*)(ws + 29884416);   // swzQ                (25165824 B)
  _Float16* Kh    = (_Float16*)(ws + 55050240);   // swzK                (25165824 B)
  _Float16* Vth   = (_Float16*)(ws + 80216064);   // swzV                (25165824 B)
  _Float16* Ctx   = (_Float16*)(ws + 105381888);  // [16384][768]        (25165824 B)

  float* out   = (float*)d_out;
  float* probs = out + 12582912;                  // [16][8][1024][1024]

  cvt_x<<<dim3(6144), dim3(256), 0, stream>>>(X, Xh);
  cvt_w<<<dim3(9216), dim3(256), 0, stream>>>(Wq, Wk, Wv, Wo, Wqkvt, Wot);
  gemm128<0, 18><<<dim3(2304), dim3(256), 0, stream>>>(Xh, Wqkvt, bq, bk, bv, Qh, Kh, Vth, nullptr);
  attn<<<dim3(8192), dim3(512), 0, stream>>>(Qh, Kh, Vth, probs, Ctx);
  gemm128<1, 6><<<dim3(768), dim3(256), 0, stream>>>(Ctx, Wot, bo, bo, bo, nullptr, nullptr, nullptr, out);
}

// Round 16
// 298.347 us; speedup vs baseline: 1.0975x; 1.0975x over previous
//
#include <hip/hip_runtime.h>

typedef _Float16 half8 __attribute__((ext_vector_type(8)));
typedef _Float16 half4 __attribute__((ext_vector_type(4)));
typedef float f32x4 __attribute__((ext_vector_type(4)));

__device__ __forceinline__ void lds_load16(const void* g, void* l) {
  __builtin_amdgcn_global_load_lds((const __attribute__((address_space(1))) void*)g,
                                   (__attribute__((address_space(3))) void*)l, 16, 0, 0);
}

__device__ __forceinline__ void lds_barrier() {
  asm volatile("s_waitcnt lgkmcnt(0)" ::: "memory");
  asm volatile("s_barrier" ::: "memory");
}

// ------- fused converts -------
// blocks 0..6143:   X f32 -> fp16 (vectorized copy)
// blocks 6144..6719: W transpose via 64x64 LDS tiles -> coalesced reads AND writes
__global__ __launch_bounds__(256) void cvt_all(const float* __restrict__ X,
                                               const float* __restrict__ Wq, const float* __restrict__ Wk,
                                               const float* __restrict__ Wv, const float* __restrict__ Wo,
                                               _Float16* __restrict__ Xh,
                                               _Float16* __restrict__ Wqkvt, _Float16* __restrict__ Wot) {
  const int bid = blockIdx.x, tid = threadIdx.x;
  if (bid < 6144) {
    int i = bid * 256 + tid;
    const float4* p = (const float4*)(X + (size_t)i * 8);
    float4 a = p[0], b = p[1];
    half8 v;
    v[0] = (_Float16)a.x; v[1] = (_Float16)a.y; v[2] = (_Float16)a.z; v[3] = (_Float16)a.w;
    v[4] = (_Float16)b.x; v[5] = (_Float16)b.y; v[6] = (_Float16)b.z; v[7] = (_Float16)b.w;
    *(half8*)(Xh + (size_t)i * 8) = v;
  } else {
    __shared__ _Float16 T[64][72];           // +8 pad: conflict-free transpose
    const int t = bid - 6144;                // 0..575
    const int part = t / 144;
    const int r = t - part * 144;
    const int k0 = (r / 12) * 64, n0 = (r - (r / 12) * 12) * 64;
    const float* W = part == 0 ? Wq : part == 1 ? Wk : part == 2 ? Wv : Wo;
    // load 64x64 f32 tile, coalesced over n (4 cols per thread via float4)
    const int lr0 = tid >> 4, lc0 = (tid & 15) * 4;
#pragma unroll
    for (int rr = 0; rr < 4; ++rr) {
      const int row = lr0 + rr * 16;
      float4 v = *(const float4*)(W + (size_t)(k0 + row) * 768 + n0 + lc0);
      T[lc0 + 0][row] = (_Float16)v.x;
      T[lc0 + 1][row] = (_Float16)v.y;
      T[lc0 + 2][row] = (_Float16)v.z;
      T[lc0 + 3][row] = (_Float16)v.w;
    }
    __syncthreads();
    // write transposed: Wt[n][k], coalesced over k (half4 per thread)
    _Float16* Wt = part < 3 ? (Wqkvt + (size_t)(part * 768 + n0) * 768 + k0)
                            : (Wot + (size_t)n0 * 768 + k0);
    const int wr0 = tid >> 4, wc0 = (tid & 15) * 4;
#pragma unroll
    for (int rr = 0; rr < 4; ++rr) {
      const int nrow = wr0 + rr * 16;
      half4 h = *(const half4*)&T[nrow][wc0];
      *(half4*)(Wt + (size_t)nrow * 768 + wc0) = h;
    }
  }
}

// ---------------- fp16 MFMA GEMM: 128x128, BK=32, 4 waves, 4 blocks/CU (R11) ----------------
template <int EPI, int NB>
__global__ __launch_bounds__(256, 4) void gemm128(
    const _Float16* __restrict__ A, const _Float16* __restrict__ Bt,
    const float* __restrict__ b0, const float* __restrict__ b1, const float* __restrict__ b2,
    _Float16* __restrict__ Qo, _Float16* __restrict__ Ko, _Float16* __restrict__ Vto,
    float* __restrict__ Co) {
  __shared__ _Float16 Ab[2][128 * 32];
  __shared__ _Float16 Bb[2][128 * 32];
  const int tid = threadIdx.x, w = tid >> 6, l = tid & 63;
  const int lr = l & 15, lk = l >> 4;
  const int wm = w >> 1, wn = w & 1;
  const int q8 = (int)gridDim.x >> 3;
  const int wg = ((int)blockIdx.x & 7) * q8 + ((int)blockIdx.x >> 3);
  const int m0 = (wg / NB) * 128, n0 = (wg % NB) * 128;

  auto STAGE = [&](int kt, int dstb) {
#pragma unroll
    for (int i = 0; i < 2; ++i) {
      const int g = i * 256 + tid;
      const int row = g >> 2;
      const int gr = (g & 3) ^ (row & 3);
      lds_load16(A + (size_t)(m0 + row) * 768 + kt * 32 + gr * 8,
                 (char*)&Ab[dstb][0] + g * 16);
      lds_load16(Bt + (size_t)(n0 + row) * 768 + kt * 32 + gr * 8,
                 (char*)&Bb[dstb][0] + g * 16);
    }
  };

  f32x4 acc[4][4] = {};
  STAGE(0, 0);
  const int swzg = ((lk ^ (lr & 3)) * 8);

  for (int T = 0; T < 24; ++T) {
    const int b = T & 1;
    asm volatile("s_waitcnt vmcnt(0)" ::: "memory");
    asm volatile("s_barrier" ::: "memory");
    if (T < 23) STAGE(T + 1, b ^ 1);
    half8 af[4], bf[4];
#pragma unroll
    for (int mi = 0; mi < 4; ++mi)
      af[mi] = *(const half8*)&Ab[b][(wm * 64 + mi * 16 + lr) * 32 + swzg];
#pragma unroll
    for (int ni = 0; ni < 4; ++ni)
      bf[ni] = *(const half8*)&Bb[b][(wn * 64 + ni * 16 + lr) * 32 + swzg];
    __builtin_amdgcn_s_setprio(1);
#pragma unroll
    for (int mi = 0; mi < 4; ++mi)
#pragma unroll
      for (int ni = 0; ni < 4; ++ni)
        acc[mi][ni] = __builtin_amdgcn_mfma_f32_16x16x32_f16(af[mi], bf[ni], acc[mi][ni], 0, 0, 0);
    __builtin_amdgcn_s_setprio(0);
  }

#pragma unroll
  for (int mi = 0; mi < 4; ++mi) {
    const int rbase = m0 + wm * 64 + mi * 16 + lk * 4;
#pragma unroll
    for (int ni = 0; ni < 4; ++ni) {
      const int col = n0 + wn * 64 + ni * 16 + lr;
      if (EPI == 0) {
        const int part = col / 768;
        const int e = col - part * 768;
        const int h = e / 96, d = e - (e / 96) * 96;
        const float* bb = part == 0 ? b0 : part == 1 ? b1 : b2;
        const float bv = bb[e];
#pragma unroll
        for (int j = 0; j < 4; ++j) {
          const int row = rbase + j;
          const int bI = row >> 10, s = row & 1023;
          const int bh = bI * 8 + h;
          const _Float16 v = (_Float16)(acc[mi][ni][j] + bv);
          if (part < 2) {
            const size_t idx = ((((size_t)(bh * 64 + (s >> 4)) * 3 + (d >> 5)) * 64
                                + ((d & 31) >> 3) * 16 + (s & 15)) << 3) + (d & 7);
            if (part == 0) Qo[idx] = v; else Ko[idx] = v;
          } else {
            const size_t idx = ((((size_t)(bh * 6 + (d >> 4)) * 32 + (s >> 5)) * 64
                                + ((s & 31) >> 3) * 16 + (d & 15)) << 3) + (s & 7);
            Vto[idx] = v;
          }
        }
      } else {
        const float bv = b0[col];
#pragma unroll
        for (int j = 0; j < 4; ++j) {
          const int row = rbase + j;
          __builtin_nontemporal_store(acc[mi][ni][j] + bv, Co + (size_t)row * 768 + col);
        }
      }
    }
  }
}

// ---------------- fused attention v11 (R14, best known) ----------------
__global__ __launch_bounds__(512, 2) void attn(const _Float16* __restrict__ swzQ,
                                               const _Float16* __restrict__ swzK,
                                               const _Float16* __restrict__ swzV,
                                               float* __restrict__ probs,
                                               _Float16* __restrict__ ctx) {
  __shared__ __align__(16) float Pf[8][16][132];
  __shared__ float lsb[8][2][16];
  const int tid = threadIdx.x, w = tid >> 6, l = tid & 63;
  const int lr = l & 15, lk = l >> 4;
  const int id = blockIdx.x;
  const int lid = (id & 7) * 512 + (id >> 3);
  const int bh = lid >> 5, qt2 = lid & 31;
  const int q0 = qt2 * 32;
  const float SC = 0.10206207261596577f * 1.4426950408889634f;
  const int b = bh >> 3, h = bh & 7;

  const half8* qbA = (const half8*)swzQ + (size_t)(bh * 64 + qt2 * 2) * 192;
  const half8* kb  = (const half8*)swzK + (size_t)(bh * 64 + w * 8) * 192;
  const half8* vb0 = (const half8*)swzV + (size_t)bh * 12288;
  half8 bqA[3], bqB[3];
#pragma unroll
  for (int kk = 0; kk < 3; ++kk) { bqA[kk] = qbA[kk * 64 + l]; bqB[kk] = qbA[192 + kk * 64 + l]; }
  half8 kf[8][3];
#pragma unroll
  for (int ct = 0; ct < 8; ++ct)
#pragma unroll
    for (int kk = 0; kk < 3; ++kk) kf[ct][kk] = kb[(ct * 3 + kk) * 64 + l];

  f32x4 sA[8], sB[8];
#pragma unroll
  for (int ct = 0; ct < 8; ++ct) {
    f32x4 aA = {0.f, 0.f, 0.f, 0.f}, aB = {0.f, 0.f, 0.f, 0.f};
#pragma unroll
    for (int kk = 0; kk < 3; ++kk) {
      aA = __builtin_amdgcn_mfma_f32_16x16x32_f16(kf[ct][kk], bqA[kk], aA, 0, 0, 0);
      aB = __builtin_amdgcn_mfma_f32_16x16x32_f16(kf[ct][kk], bqB[kk], aB, 0, 0, 0);
    }
    sA[ct] = aA; sB[ct] = aB;
  }

  float psA = 0.f, psB = 0.f;
#pragma unroll
  for (int ct = 0; ct < 8; ++ct)
#pragma unroll
    for (int j = 0; j < 4; ++j) {
      const float eA = __builtin_amdgcn_exp2f(sA[ct][j] * SC);
      const float eB = __builtin_amdgcn_exp2f(sB[ct][j] * SC);
      sA[ct][j] = eA; psA += eA;
      sB[ct][j] = eB; psB += eB;
    }
  psA += __shfl_xor(psA, 16); psA += __shfl_xor(psA, 32);
  psB += __shfl_xor(psB, 16); psB += __shfl_xor(psB, 32);
  if (lk == 0) { lsb[w][0][lr] = psA; lsb[w][1][lr] = psB; }

  half8 vf[6][4];
#pragma unroll
  for (int dt = 0; dt < 6; ++dt)
#pragma unroll
    for (int kk = 0; kk < 4; ++kk) vf[dt][kk] = vb0[(dt * 32 + w * 4 + kk) * 64 + l];

  lds_barrier();                                     // B1
  float ltA = 0.f, ltB = 0.f;
#pragma unroll
  for (int ww = 0; ww < 8; ++ww) { ltA += lsb[ww][0][lr]; ltB += lsb[ww][1][lr]; }
  const float invlA = 1.f / ltA, invlB = 1.f / ltB;

  const int qh = l >> 5, c4 = (l & 31) * 4;
  float* cbw = (float*)&Pf[w][0][0];
  const int rq = tid >> 5;
  const int rd0 = (tid & 31) * 3;

  // ---- phase A ----
#pragma unroll
  for (int ct = 0; ct < 8; ++ct) {
    f32x4 p4;
#pragma unroll
    for (int j = 0; j < 4; ++j) p4[j] = sA[ct][j] * invlA;
    *(f32x4*)&Pf[w][lr][ct * 16 + lk * 4] = p4;
  }
  {
    float* pbase = probs + ((size_t)bh << 20) + (size_t)q0 * 1024 + w * 128;
#pragma unroll
    for (int r2 = 0; r2 < 8; ++r2) {
      const int q = r2 * 2 + qh;
      f32x4 v = *(const f32x4*)&Pf[w][q][c4];
      __builtin_nontemporal_store(v, (f32x4*)(pbase + (size_t)q * 1024 + c4));
    }
  }
  f32x4 cacc[6] = {};
#pragma unroll
  for (int kk = 0; kk < 4; ++kk) {
    f32x4 a0 = *(const f32x4*)&Pf[w][lr][kk * 32 + lk * 8];
    f32x4 a1 = *(const f32x4*)&Pf[w][lr][kk * 32 + lk * 8 + 4];
    half8 pa;
#pragma unroll
    for (int e = 0; e < 4; ++e) { pa[e] = (_Float16)a0[e]; pa[4 + e] = (_Float16)a1[e]; }
#pragma unroll
    for (int dt = 0; dt < 6; ++dt)
      cacc[dt] = __builtin_amdgcn_mfma_f32_16x16x32_f16(pa, vf[dt][kk], cacc[dt], 0, 0, 0);
  }
#pragma unroll
  for (int dt = 0; dt < 6; ++dt)
#pragma unroll
    for (int j = 0; j < 4; ++j)
      cbw[(lk * 4 + j) * 100 + dt * 16 + lr] = cacc[dt][j];
  lds_barrier();                                     // B2
  {
    _Float16* cg = ctx + ((size_t)(b * 1024 + q0 + rq)) * 768 + h * 96 + rd0;
#pragma unroll
    for (int e = 0; e < 3; ++e) {
      float v = 0.f;
#pragma unroll
      for (int ww = 0; ww < 8; ++ww) v += ((const float*)&Pf[ww][0][0])[rq * 100 + rd0 + e];
      cg[e] = (_Float16)v;
    }
  }
  lds_barrier();                                     // B3

  // ---- phase B ----
#pragma unroll
  for (int ct = 0; ct < 8; ++ct) {
    f32x4 p4;
#pragma unroll
    for (int j = 0; j < 4; ++j) p4[j] = sB[ct][j] * invlB;
    *(f32x4*)&Pf[w][lr][ct * 16 + lk * 4] = p4;
  }
  {
    float* pbase = probs + ((size_t)bh << 20) + (size_t)(q0 + 16) * 1024 + w * 128;
#pragma unroll
    for (int r2 = 0; r2 < 8; ++r2) {
      const int q = r2 * 2 + qh;
      f32x4 v = *(const f32x4*)&Pf[w][q][c4];
      __builtin_nontemporal_store(v, (f32x4*)(pbase + (size_t)q * 1024 + c4));
    }
  }
#pragma unroll
  for (int dt = 0; dt < 6; ++dt) cacc[dt] = f32x4{0.f, 0.f, 0.f, 0.f};
#pragma unroll
  for (int kk = 0; kk < 4; ++kk) {
    f32x4 a0 = *(const f32x4*)&Pf[w][lr][kk * 32 + lk * 8];
    f32x4 a1 = *(const f32x4*)&Pf[w][lr][kk * 32 + lk * 8 + 4];
    half8 pa;
#pragma unroll
    for (int e = 0; e < 4; ++e) { pa[e] = (_Float16)a0[e]; pa[4 + e] = (_Float16)a1[e]; }
#pragma unroll
    for (int dt = 0; dt < 6; ++dt)
      cacc[dt] = __builtin_amdgcn_mfma_f32_16x16x32_f16(pa, vf[dt][kk], cacc[dt], 0, 0, 0);
  }
#pragma unroll
  for (int dt = 0; dt < 6; ++dt)
#pragma unroll
    for (int j = 0; j < 4; ++j)
      cbw[(lk * 4 + j) * 100 + dt * 16 + lr] = cacc[dt][j];
  lds_barrier();                                     // B4
  {
    _Float16* cg = ctx + ((size_t)(b * 1024 + q0 + 16 + rq)) * 768 + h * 96 + rd0;
#pragma unroll
    for (int e = 0; e < 3; ++e) {
      float v = 0.f;
#pragma unroll
      for (int ww = 0; ww < 8; ++ww) v += ((const float*)&Pf[ww][0][0])[rq * 100 + rd0 + e];
      cg[e] = (_Float16)v;
    }
  }
}

extern "C" void kernel_launch(void* const* d_in, const int* in_sizes, int n_in,
                              void* d_out, int out_size, void* d_ws, size_t ws_size,
                              hipStream_t stream) {
  (void)in_sizes; (void)n_in; (void)out_size; (void)ws_size;
  const float* X  = (const float*)d_in[0];
  const float* Wq = (const float*)d_in[1];
  const float* bq = (const float*)d_in[2];
  const float* Wk = (const float*)d_in[3];
  const float* bk = (const float*)d_in[4];
  const float* Wv = (const float*)d_in[5];
  const float* bv = (const float*)d_in[6];
  const float* Wo = (const float*)d_in[7];
  const float* bo = (const float*)d_in[8];

  char* ws = (char*)d_ws;
  _Float16* Xh    = (_Float16*)(ws + 0);          // 16384x768 fp16      (25165824 B)
  _Float16* Wqkvt = (_Float16*)(ws + 25165824);   // 2304x768 fp16       ( 3538944 B)
  _Float16* Wot   = (_Float16*)(ws + 28704768);   // 768x768 fp16        ( 1179648 B)
  _Float16* Qh    = (_Float16*)(ws + 29884416);   // swzQ                (25165824 B)
  _Float16* Kh    = (_Float16*)(ws + 55050240);   // swzK                (25165824 B)
  _Float16* Vth   = (_Float16*)(ws + 80216064);   // swzV                (25165824 B)
  _Float16* Ctx   = (_Float16*)(ws + 105381888);  // [16384][768]        (25165824 B)

  float* out   = (float*)d_out;
  float* probs = out + 12582912;                  // [16][8][1024][1024]

  cvt_all<<<dim3(6720), dim3(256), 0, stream>>>(X, Wq, Wk, Wv, Wo, Xh, Wqkvt, Wot);
  gemm128<0, 18><<<dim3(2304), dim3(256), 0, stream>>>(Xh, Wqkvt, bq, bk, bv, Qh, Kh, Vth, nullptr);
  attn<<<dim3(4096), dim3(512), 0, stream>>>(Qh, Kh, Vth, probs, Ctx);
  gemm128<1, 6><<<dim3(768), dim3(256), 0, stream>>>(Ctx, Wot, bo, bo, bo, nullptr, nullptr, nullptr, out);
}